// Round 11
// baseline (44.800 us; speedup 1.0000x reference)
//
#include <hip/hip_runtime.h>
#include <math.h>

#define NH 8            // heads
#define HD 32           // head dim
#define MD 128          // max dist
#define NW 257          // 2*MD+1
#define NWP 272         // padded to 17*16
#define WSM 64          // smoothed PE width
#define NB 4            // batch
#define NL 2048         // length
#define NC 64           // channels
#define NHD 256         // NH*HD
#define ROWS 128        // output rows per block
#define WIN 384         // ROWS + 2*MD
#define SPQ 40          // qu/sp LDS row stride (80B, 16B-aligned)
// 32^-0.5 * log2(e): scores land in log2 domain -> exp2f directly
#define SC2 0.2550928063161107f

// LDS offsets in u16 elements
#define QU_OFF 0
#define KT_OFF (WIN * SPQ)                 // 15360
#define QVT_OFF (KT_OFF + ROWS * HD)       // 19456
#define WT_OFF (QVT_OFF + ROWS * HD)       // 23552
#define SMEM_N (WT_OFF + 2 * 32 * 72)      // 28160 u16 = 56320 B
#define SP_OFF KT_OFF                      // smooth-PE overlays kt+qvt+wt after frag extraction

using bf16x8 = __attribute__((ext_vector_type(8))) short;
using f32x4  = __attribute__((ext_vector_type(4))) float;
using i32x4  = __attribute__((ext_vector_type(4))) int;

__device__ __forceinline__ unsigned cvtpk(float lo, float hi) {
  unsigned r;
  asm("v_cvt_pk_bf16_f32 %0, %1, %2" : "=v"(r) : "v"(lo), "v"(hi));
  return r;
}

// x row (64 fp32) -> two bf16x8 A-fragments (k 0..31 / 32..63), zero if !ok
__device__ __forceinline__ void ldx_frag(const float* xrow, bool ok, int g8,
                                         bf16x8* A0, bf16x8* A1) {
  float4 x00 = {0.f, 0.f, 0.f, 0.f}, x01 = x00, x10 = x00, x11 = x00;
  if (ok) {
    x00 = *reinterpret_cast<const float4*>(xrow + g8);
    x01 = *reinterpret_cast<const float4*>(xrow + g8 + 4);
    x10 = *reinterpret_cast<const float4*>(xrow + 32 + g8);
    x11 = *reinterpret_cast<const float4*>(xrow + 32 + g8 + 4);
  }
  const i32x4 a0i = {(int)cvtpk(x00.x, x00.y), (int)cvtpk(x00.z, x00.w),
                     (int)cvtpk(x01.x, x01.y), (int)cvtpk(x01.z, x01.w)};
  const i32x4 a1i = {(int)cvtpk(x10.x, x10.y), (int)cvtpk(x10.z, x10.w),
                     (int)cvtpk(x11.x, x11.y), (int)cvtpk(x11.z, x11.w)};
  *A0 = __builtin_bit_cast(bf16x8, a0i);
  *A1 = __builtin_bit_cast(bf16x8, a1i);
}

// ---------------- fully fused: proj (MFMA, in-LDS) + band + PE + softmax + reduce ----------------
__global__ __launch_bounds__(512, 4) void fused_kernel(
    const float* __restrict__ x,
    const float* __restrict__ Wq, const float* __restrict__ bq,
    const float* __restrict__ Wk, const float* __restrict__ bk,
    const float* __restrict__ Wv, const float* __restrict__ dpe,
    const float* __restrict__ u_pe, const float* __restrict__ v_pe,
    float* __restrict__ out) {
  __shared__ __align__(16) unsigned short lds[SMEM_N];
  __shared__ __align__(16) float vvl[ROWS];

  const int bid = blockIdx.x;
  const int tile = bid & 15;          // 16 tiles of 128 rows
  const int hb = bid >> 4;            // h*NB + b
  const int b = hb & (NB - 1);
  const int h = hb >> 2;
  const int hc0 = h * HD;
  const int n0 = tile << 7;
  const int jlo = NL - ROWS - n0;     // k rows jlo..jlo+127
  const int wq0 = jlo - MD;           // first qu-window q-row (may be <0)
  const int tid = threadIdx.x;
  const int l = tid & 63;
  const int w = tid >> 6;             // wave 0..7
  const int c = l & 15;
  const int g = l >> 4;
  const int g8 = g * 8;

  const float* xb = x + (size_t)b * NL * NC;

  // ---- phase 1a: stage W^T for head h as bf16 [2][32 col][72 k-stride] ----
#pragma unroll
  for (int i = 0; i < 4; ++i) {
    const int flat = tid + i * 512;   // 0..2047
    const int col = flat & 31;
    const int kp = (flat >> 5) & 31;  // k-pair
    const int ws = flat >> 10;        // 0: Wq, 1: Wk
    const float* Wsrc = ws ? Wk : Wq;
    const float w0 = Wsrc[(2 * kp) * NHD + hc0 + col];
    const float w1 = Wsrc[(2 * kp + 1) * NHD + hc0 + col];
    *reinterpret_cast<unsigned*>(&lds[WT_OFF + ((ws * 32 + col) * 72 + 2 * kp)]) = cvtpk(w0, w1);
  }
  // sigmoid-v for rows n0..n0+127 (Wv loads are wave-uniform)
  if (tid < ROWS) {
    const float* xr = xb + (size_t)(n0 + tid) * NC;
    float a = 0.f;
#pragma unroll
    for (int k4 = 0; k4 < NC / 4; ++k4) {
      const float4 xv = *reinterpret_cast<const float4*>(xr + 4 * k4);
      a = fmaf(xv.x, Wv[(4 * k4 + 0) * NH + h], a);
      a = fmaf(xv.y, Wv[(4 * k4 + 1) * NH + h], a);
      a = fmaf(xv.z, Wv[(4 * k4 + 2) * NH + h], a);
      a = fmaf(xv.w, Wv[(4 * k4 + 3) * NH + h], a);
    }
    vvl[tid] = 1.f / (1.f + __expf(-a));
  }
  __syncthreads();

  // ---- phase 1b: B-fragments from W^T; biases ----
  bf16x8 bw[2][2][2];                 // [ws][ct][ks]
#pragma unroll
  for (int ws = 0; ws < 2; ++ws)
#pragma unroll
    for (int ct = 0; ct < 2; ++ct)
#pragma unroll
      for (int ks = 0; ks < 2; ++ks)
        bw[ws][ct][ks] = *reinterpret_cast<const bf16x8*>(
            &lds[WT_OFF + ((ws * 32 + ct * 16 + c) * 72 + ks * 32 + g8)]);

  float biasQU[2], biasQV[2], biasK[2];
#pragma unroll
  for (int ct = 0; ct < 2; ++ct) {
    const int d = ct * 16 + c;
    const float bqv = bq[hc0 + d];
    biasQU[ct] = bqv + u_pe[hc0 + d];
    biasQV[ct] = bqv + v_pe[hc0 + d];
    biasK[ct] = bk[hc0 + d];
  }

  const f32x4 z4 = {0.f, 0.f, 0.f, 0.f};

  // ---- phase 1c: proj MFMAs -> LDS tiles. C-layout: row(x-row)=4g+r, col(W-col)=c ----
  // (a) qu window: 3 row-tiles/wave, OOB rows -> 0
#pragma unroll
  for (int rt = 0; rt < 3; ++rt) {
    const int wr0 = 48 * w + 16 * rt;
    const int gr = wq0 + wr0 + c;
    bf16x8 a0, a1;
    ldx_frag(xb + (size_t)gr * NC, (unsigned)gr < (unsigned)NL, g8, &a0, &a1);
    f32x4 acc0 = z4, acc1 = z4;
    acc0 = __builtin_amdgcn_mfma_f32_16x16x32_bf16(a0, bw[0][0][0], acc0, 0, 0, 0);
    acc0 = __builtin_amdgcn_mfma_f32_16x16x32_bf16(a1, bw[0][0][1], acc0, 0, 0, 0);
    acc1 = __builtin_amdgcn_mfma_f32_16x16x32_bf16(a0, bw[0][1][0], acc1, 0, 0, 0);
    acc1 = __builtin_amdgcn_mfma_f32_16x16x32_bf16(a1, bw[0][1][1], acc1, 0, 0, 0);
#pragma unroll
    for (int ct = 0; ct < 2; ++ct) {
      const f32x4 acc = ct ? acc1 : acc0;
      const int d = ct * 16 + c;
#pragma unroll
      for (int r = 0; r < 4; ++r) {
        const int wr = wr0 + 4 * g + r;
        const float val = ((unsigned)(wq0 + wr) < (unsigned)NL) ? acc[r] + biasQU[ct] : 0.f;
        lds[QU_OFF + wr * SPQ + d] = (unsigned short)cvtpk(val, val);
      }
    }
  }
  // (b) k tile (pre-scaled by SC2)
  {
    const int gr = jlo + 16 * w + c;
    bf16x8 a0, a1;
    ldx_frag(xb + (size_t)gr * NC, true, g8, &a0, &a1);
    f32x4 acc0 = z4, acc1 = z4;
    acc0 = __builtin_amdgcn_mfma_f32_16x16x32_bf16(a0, bw[1][0][0], acc0, 0, 0, 0);
    acc0 = __builtin_amdgcn_mfma_f32_16x16x32_bf16(a1, bw[1][0][1], acc0, 0, 0, 0);
    acc1 = __builtin_amdgcn_mfma_f32_16x16x32_bf16(a0, bw[1][1][0], acc1, 0, 0, 0);
    acc1 = __builtin_amdgcn_mfma_f32_16x16x32_bf16(a1, bw[1][1][1], acc1, 0, 0, 0);
#pragma unroll
    for (int ct = 0; ct < 2; ++ct) {
      const f32x4 acc = ct ? acc1 : acc0;
#pragma unroll
      for (int r = 0; r < 4; ++r) {
        const float val = (acc[r] + biasK[ct]) * SC2;
        lds[KT_OFF + (16 * w + 4 * g + r) * HD + ct * 16 + c] = (unsigned short)cvtpk(val, val);
      }
    }
  }
  // (c) qv tile (q + v_pe)
  {
    const int gr = n0 + 16 * w + c;
    bf16x8 a0, a1;
    ldx_frag(xb + (size_t)gr * NC, true, g8, &a0, &a1);
    f32x4 acc0 = z4, acc1 = z4;
    acc0 = __builtin_amdgcn_mfma_f32_16x16x32_bf16(a0, bw[0][0][0], acc0, 0, 0, 0);
    acc0 = __builtin_amdgcn_mfma_f32_16x16x32_bf16(a1, bw[0][0][1], acc0, 0, 0, 0);
    acc1 = __builtin_amdgcn_mfma_f32_16x16x32_bf16(a0, bw[0][1][0], acc1, 0, 0, 0);
    acc1 = __builtin_amdgcn_mfma_f32_16x16x32_bf16(a1, bw[0][1][1], acc1, 0, 0, 0);
#pragma unroll
    for (int ct = 0; ct < 2; ++ct) {
      const f32x4 acc = ct ? acc1 : acc0;
#pragma unroll
      for (int r = 0; r < 4; ++r) {
        const float val = acc[r] + biasQV[ct];
        lds[QVT_OFF + (16 * w + 4 * g + r) * HD + ct * 16 + c] = (unsigned short)cvtpk(val, val);
      }
    }
  }
  __syncthreads();

  // ---- phase 2: extract band fragments, then overlay smooth-PE on dead tiles ----
  const bf16x8 ak  = *reinterpret_cast<const bf16x8*>(&lds[KT_OFF + (16 * w + c) * HD + g8]);
  const bf16x8 aqv = *reinterpret_cast<const bf16x8*>(&lds[QVT_OFF + (ROWS - 1 - 16 * w - c) * HD + g8]);
  const f32x4 v4 = *reinterpret_cast<const f32x4*>(&vvl[ROWS - 4 - 16 * w - 4 * g]);
  __syncthreads();   // frag reads complete before sp overwrites kt/qvt/wt

#pragma unroll
  for (int i = 0; i < 17; ++i) {      // 272*32 / 512 threads
    const int idx = tid + i * 512;
    const int d = idx & 31, m = idx >> 5;
    float val = 0.f;
    if (m < NW) {
      float t2 = (m + 0.5f) * ((float)WSM / (float)NW) - 0.5f;
      t2 = fminf(fmaxf(t2, 0.f), (float)(WSM - 1));
      const int i0 = (int)t2;
      const float f = t2 - (float)i0;
      const int i1 = (i0 + 1 < WSM) ? i0 + 1 : WSM - 1;
      const float* bse = dpe + (size_t)(hc0 + d) * WSM;
      val = (bse[i0] * (1.f - f) + bse[i1] * f) * SC2;
    }
    lds[SP_OFF + m * SPQ + d] = (unsigned short)cvtpk(val, val);
  }
  __syncthreads();

  // ---- phase 3: PE MFMAs + band MFMAs + realign + softmax + gate + reduce ----
  f32x4 s[17];
#pragma unroll
  for (int t = 0; t < 17; ++t) {
    const bf16x8 bsp = *reinterpret_cast<const bf16x8*>(&lds[SP_OFF + (16 * t + c) * SPQ + g8]);
    s[t] = __builtin_amdgcn_mfma_f32_16x16x32_bf16(aqv, bsp, z4, 0, 0, 0);
  }

  int sl[4]; bool cond[4];
#pragma unroll
  for (int r = 0; r < 4; ++r) {
    sl[r] = 16 * g + ((4 * g + r - c) & 15);
    cond[r] = (4 * g + r) >= c;
  }

  f32x4 shp;
#pragma unroll
  for (int U = 0; U <= 16; ++U) {
    const bf16x8 bqu = *reinterpret_cast<const bf16x8*>(&lds[QU_OFF + (16 * w + 16 * U + c) * SPQ + g8]);
    const f32x4 c1 = __builtin_amdgcn_mfma_f32_16x16x32_bf16(ak, bqu, z4, 0, 0, 0);
    f32x4 shc;
#pragma unroll
    for (int r = 0; r < 4; ++r) shc[r] = __shfl(c1[r], sl[r], 64);
    if (U == 0) {
#pragma unroll
      for (int r = 0; r < 4; ++r)
        s[16][r] = (c == 0) ? (s[16][r] + shc[r]) : -1e30f;  // m=256+c valid only c==0
    } else {
#pragma unroll
      for (int r = 0; r < 4; ++r)
        s[16 - U][r] += cond[r] ? shc[r] : shp[r];
    }
    shp = shc;
  }

  float wgt[4];
#pragma unroll
  for (int r = 0; r < 4; ++r) {
    float sum = 0.f;
#pragma unroll
    for (int t = 0; t < 17; ++t) {
      const float p = exp2f(s[t][r]);
      s[t][r] = p;
      sum += p;
    }
#pragma unroll
    for (int off = 1; off < 16; off <<= 1) sum += __shfl_xor(sum, off, 16);
    wgt[r] = v4[3 - r] * __builtin_amdgcn_rcpf(sum);  // v[n], n = n0+127-(16w+4g+r)
  }

  __syncthreads();  // all waves done reading qu_sh; reuse as reduction buffer
  float* red = reinterpret_cast<float*>(&lds[QU_OFF]);
#pragma unroll
  for (int t = 0; t < 17; ++t) {
    float y = s[t][0] * wgt[0] + s[t][1] * wgt[1] + s[t][2] * wgt[2] + s[t][3] * wgt[3];
    y += __shfl_xor(y, 16, 64);
    y += __shfl_xor(y, 32, 64);
    if (l < 16) red[w * NWP + 16 * t + c] = y;
  }
  __syncthreads();
  for (int m = tid; m < NW; m += 512) {
    float ssum = 0.f;
#pragma unroll
    for (int ww = 0; ww < 8; ++ww) ssum += red[ww * NWP + m];
    atomicAdd(&out[((size_t)b * NW + m) * NH + h], ssum);
  }
}

extern "C" void kernel_launch(void* const* d_in, const int* in_sizes, int n_in,
                              void* d_out, int out_size, void* d_ws, size_t ws_size,
                              hipStream_t stream) {
  const float* x = (const float*)d_in[0];
  const float* Wq = (const float*)d_in[1];
  const float* bq = (const float*)d_in[2];
  const float* Wk = (const float*)d_in[3];
  const float* bk = (const float*)d_in[4];
  const float* Wv = (const float*)d_in[5];
  const float* dpe = (const float*)d_in[6];
  const float* u_pe = (const float*)d_in[7];
  const float* v_pe = (const float*)d_in[8];
  float* out = (float*)d_out;

  hipMemsetAsync(d_out, 0, (size_t)out_size * sizeof(float), stream);
  hipLaunchKernelGGL(fused_kernel, dim3(NH * NB * (NL / ROWS)), dim3(512), 0, stream,
                     x, Wq, bq, Wk, bk, Wv, dpe, u_pe, v_pe, out);
}

// Round 12
// 33.864 us; speedup vs baseline: 1.3229x; 1.3229x over previous
//
#include <hip/hip_runtime.h>
#include <math.h>

#define NH 8            // heads
#define HD 32           // head dim
#define MD 128          // max dist
#define NW 257          // 2*MD+1
#define NWP 272         // padded to 17*16
#define WSM 64          // smoothed PE width
#define NB 4            // batch
#define NL 2048         // length
#define NC 64           // channels
#define NHD 256         // NH*HD
#define SP 40           // padded LDS row stride in bf16 elems (80B)
#define ROWS 128        // output rows per band block
#define WIN 384         // ROWS + 2*MD
// 32^-0.5 * log2(e): scores land in log2 domain -> exp2f directly
#define SC2 0.2550928063161107f

#define PM_BLK 512      // MFMA proj blocks: 128 row-tiles x 4 col-tiles
#define VV_BLK 64       // sigmoid-v tail blocks (128 rows each)
#define SPE_BLK 34      // smooth-PE + out-zero tail blocks
#define WTS 72          // W^T LDS stride in u16 (144B: 16B-aligned, 2-way bank aliasing = free)

using bf16x8 = __attribute__((ext_vector_type(8))) short;
using f32x4  = __attribute__((ext_vector_type(4))) float;
using i32x4  = __attribute__((ext_vector_type(4))) int;

__device__ __forceinline__ unsigned cvtpk(float lo, float hi) {
  unsigned r;
  asm("v_cvt_pk_bf16_f32 %0, %1, %2" : "=v"(r) : "v"(lo), "v"(hi));
  return r;
}
__device__ __forceinline__ void stb(unsigned short* p, float f) {
  *p = (unsigned short)cvtpk(f, f);   // RNE bf16, low half
}

// ---- MFMA projections (qu=q+u_pe, qv=q+v_pe, kb=k*SC2 bf16) + tails: vv sigmoid,
// ---- smooth-PE table (pre-scaled), d_out zeroing. All tail outputs feed the NEXT launch.
__global__ __launch_bounds__(256, 4) void projmm_kernel(
    const float* __restrict__ x,
    const float* __restrict__ Wq, const float* __restrict__ bq,
    const float* __restrict__ Wk, const float* __restrict__ bk,
    const float* __restrict__ Wv, const float* __restrict__ dpe,
    const float* __restrict__ u_pe, const float* __restrict__ v_pe,
    unsigned short* __restrict__ qu, unsigned short* __restrict__ qv,
    unsigned short* __restrict__ kb, float* __restrict__ vv,
    unsigned short* __restrict__ spt, float* __restrict__ out) {
  __shared__ __align__(16) unsigned short wt[128 * WTS];   // W^T tile: [col 0..127][k 0..63]
  const int t = threadIdx.x;
  const int bid = blockIdx.x;

  if (bid >= PM_BLK + VV_BLK) {
    // ---- spe + zero-out tail ----
    const int base = (bid - PM_BLK - VV_BLK) * 256 + t;
    if (base < NB * NW * NH) out[base] = 0.f;
    for (int idx = base; idx < NH * NWP * HD; idx += SPE_BLK * 256) {
      const int d = idx & 31;
      const int hm = idx >> 5;
      const int m = hm % NWP;
      const int h = hm / NWP;
      float val = 0.f;
      if (m < NW) {
        float tt = (m + 0.5f) * ((float)WSM / (float)NW) - 0.5f;
        tt = fminf(fmaxf(tt, 0.f), (float)(WSM - 1));
        const int i0 = (int)tt;
        const float f = tt - (float)i0;
        const int i1 = (i0 + 1 < WSM) ? i0 + 1 : WSM - 1;
        const float* bse = dpe + ((size_t)h * HD + d) * WSM;
        val = (bse[i0] * (1.f - f) + bse[i1] * f) * SC2;
      }
      stb(spt + idx, val);
    }
    return;
  }

  if (bid >= PM_BLK) {
    // ---- vv tail: v = sigmoid(x @ Wv), 128 rows/block, 2 threads/row x 4 heads ----
    const int row = (bid - PM_BLK) * 128 + (t >> 1);
    const int h0 = (t & 1) * 4;
    const float* xr = x + (size_t)row * NC;
    float a0 = 0.f, a1 = 0.f, a2 = 0.f, a3 = 0.f;
#pragma unroll
    for (int c4 = 0; c4 < NC / 4; ++c4) {
      const float4 xv = *reinterpret_cast<const float4*>(xr + 4 * c4);
#pragma unroll
      for (int j = 0; j < 4; ++j) {
        const float xs = j == 0 ? xv.x : j == 1 ? xv.y : j == 2 ? xv.z : xv.w;
        const float4 wv = *reinterpret_cast<const float4*>(Wv + (4 * c4 + j) * NH + h0);
        a0 = fmaf(xs, wv.x, a0);
        a1 = fmaf(xs, wv.y, a1);
        a2 = fmaf(xs, wv.z, a2);
        a3 = fmaf(xs, wv.w, a3);
      }
    }
    const int b = row >> 11, ll = row & (NL - 1);
    vv[((size_t)(h0 + 0) * NB + b) * NL + ll] = 1.f / (1.f + __expf(-a0));
    vv[((size_t)(h0 + 1) * NB + b) * NL + ll] = 1.f / (1.f + __expf(-a1));
    vv[((size_t)(h0 + 2) * NB + b) * NL + ll] = 1.f / (1.f + __expf(-a2));
    vv[((size_t)(h0 + 3) * NB + b) * NL + ll] = 1.f / (1.f + __expf(-a3));
    return;
  }

  // ---- MFMA proj: block = 64 rows x 128 cols of the 512-wide concat(q,k) output ----
  const int l64 = t & 63, w = t >> 6;
  const int c = l64 & 15, g = l64 >> 4, g8 = g * 8;
  const int br = bid >> 2;
  const int c0 = (bid & 3) << 7;       // 0,128 -> q cols; 256,384 -> k cols (block-uniform)
  const int r0 = br << 6;
  const int b = r0 >> 11;
  const int l0 = r0 & (NL - 1);

  const bool isQ = (c0 < 256);
  const float* Wsrc = isQ ? Wq : Wk;
  const int cb = isQ ? c0 : c0 - 256;

  // ---- stage W^T tile (128 cols x 64 k) as bf16: coalesced float4 loads + packed writes ----
#pragma unroll
  for (int i = 0; i < 4; ++i) {
    const int flat = t + i * 256;      // 0..1023 = (col4 0..31) x (kpair 0..31)
    const int col4 = flat & 31;
    const int kp = flat >> 5;
    const float4 w0 = *reinterpret_cast<const float4*>(Wsrc + (2 * kp) * NHD + cb + 4 * col4);
    const float4 w1 = *reinterpret_cast<const float4*>(Wsrc + (2 * kp + 1) * NHD + cb + 4 * col4);
    unsigned* wp = reinterpret_cast<unsigned*>(wt);
    wp[(4 * col4 + 0) * (WTS / 2) + kp] = cvtpk(w0.x, w1.x);
    wp[(4 * col4 + 1) * (WTS / 2) + kp] = cvtpk(w0.y, w1.y);
    wp[(4 * col4 + 2) * (WTS / 2) + kp] = cvtpk(w0.z, w1.z);
    wp[(4 * col4 + 3) * (WTS / 2) + kp] = cvtpk(w0.w, w1.w);
  }

  // A fragments: x rows (fp32 -> bf16 in-register); lane c = row, g = k-chunk
  const float* xr = x + (size_t)(r0 + 16 * w + c) * NC;
  const float4 x00 = *reinterpret_cast<const float4*>(xr + g8);
  const float4 x01 = *reinterpret_cast<const float4*>(xr + g8 + 4);
  const float4 x10 = *reinterpret_cast<const float4*>(xr + 32 + g8);
  const float4 x11 = *reinterpret_cast<const float4*>(xr + 32 + g8 + 4);
  const i32x4 a0i = {(int)cvtpk(x00.x, x00.y), (int)cvtpk(x00.z, x00.w),
                     (int)cvtpk(x01.x, x01.y), (int)cvtpk(x01.z, x01.w)};
  const i32x4 a1i = {(int)cvtpk(x10.x, x10.y), (int)cvtpk(x10.z, x10.w),
                     (int)cvtpk(x11.x, x11.y), (int)cvtpk(x11.z, x11.w)};
  const bf16x8 a0 = __builtin_bit_cast(bf16x8, a0i);
  const bf16x8 a1 = __builtin_bit_cast(bf16x8, a1i);

  __syncthreads();

  f32x4 acc[8];
#pragma unroll
  for (int tt = 0; tt < 8; ++tt) acc[tt] = {0.f, 0.f, 0.f, 0.f};

#pragma unroll
  for (int tt = 0; tt < 8; ++tt) {
    const bf16x8 b0 = *reinterpret_cast<const bf16x8*>(&wt[(16 * tt + c) * WTS + g8]);
    const bf16x8 b1 = *reinterpret_cast<const bf16x8*>(&wt[(16 * tt + c) * WTS + 32 + g8]);
    acc[tt] = __builtin_amdgcn_mfma_f32_16x16x32_bf16(a0, b0, acc[tt], 0, 0, 0);
    acc[tt] = __builtin_amdgcn_mfma_f32_16x16x32_bf16(a1, b1, acc[tt], 0, 0, 0);
  }

  // epilogue: D row = 4g+r (x-row within wave tile), col = c (m89-verified layout)
#pragma unroll
  for (int tt = 0; tt < 8; ++tt) {
    const int col = cb + 16 * tt + c;
    const int h = col >> 5, d = col & 31;
    const size_t rowbase = (((size_t)h * NB + b) * NL + l0 + 16 * w) * HD + d;
    if (isQ) {
      const float bias = bq[col];
      const float uu = u_pe[col], vp = v_pe[col];
#pragma unroll
      for (int r = 0; r < 4; ++r) {
        const float val = acc[tt][r] + bias;
        stb(qu + rowbase + (size_t)(4 * g + r) * HD, val + uu);
        stb(qv + rowbase + (size_t)(4 * g + r) * HD, val + vp);
      }
    } else {
      const float bias = bk[col];
#pragma unroll
      for (int r = 0; r < 4; ++r)
        stb(kb + rowbase + (size_t)(4 * g + r) * HD, (acc[tt][r] + bias) * SC2);
    }
  }
}

// ---------- main: 128-row tiles, 8 waves (2 blocks/CU). PE MFMAs pre-barrier
// ---------- (direct-global sp, latency-hidden vs qu staging); band post-barrier from LDS.
__global__ __launch_bounds__(512, 4) void band_attn_mfma(
    const unsigned short* __restrict__ qu, const unsigned short* __restrict__ qv,
    const unsigned short* __restrict__ kb, const float* __restrict__ vv,
    const unsigned short* __restrict__ spt, float* __restrict__ out) {
  __shared__ __align__(16) unsigned short qu_sh[WIN * SP];  // 384 rows, stride-40: 30.7 KB
  float* red = reinterpret_cast<float*>(qu_sh);             // overlay (8*NWP*4 = 8.7 KB)

  const int bid = blockIdx.x;
  const int tile = bid & 15;          // 16 tiles of 128 rows
  const int hb = bid >> 4;            // h*NB + b
  const int b = hb & (NB - 1);
  const int h = hb >> 2;
  const int n0 = tile << 7;
  const int jlo = NL - ROWS - n0;     // k rows jlo..jlo+127
  const int tid = threadIdx.x;
  const int l = tid & 63;
  const int w = tid >> 6;             // wave 0..7: k-row group 16w..16w+15
  const int c = l & 15;
  const int g = l >> 4;
  const int g8 = g * 8;

  const unsigned short* qu_h = qu + (size_t)hb * NL * HD;
  const unsigned short* qv_h = qv + (size_t)hb * NL * HD;
  const unsigned short* k_h  = kb + (size_t)hb * NL * HD;
  const unsigned short* sp_h = spt + (size_t)h * NWP * HD;
  const float* vv_h = vv + (size_t)hb * NL;

  // A fragments + v-gate (global, earliest issue)
  const bf16x8 ak  = *reinterpret_cast<const bf16x8*>(k_h  + (size_t)(jlo + 16 * w + c) * HD + g8);
  const bf16x8 aqv = *reinterpret_cast<const bf16x8*>(qv_h + (size_t)(n0 + 127 - 16 * w - c) * HD + g8);
  const f32x4 v4 = *reinterpret_cast<const f32x4*>(vv_h + (n0 + 124 - 16 * w - 4 * g));

  // qu staging loads issued BEFORE the PE chain (their RTT completes under PE compute)
  const int wq0_blk = jlo - MD;       // global row of qu_sh row 0 (may be <0)
  i32x4 stq[3];
#pragma unroll
  for (int it = 0; it < 3; ++it) {    // 384 rows * 4 chunks / 512 threads
    const int p = tid + it * 512;
    const int gr = wq0_blk + (p >> 2);
    i32x4 val = {0, 0, 0, 0};
    if ((unsigned)gr < (unsigned)NL)
      val = *reinterpret_cast<const i32x4*>(qu_h + (size_t)gr * HD + (p & 3) * 8);
    stq[it] = val;
  }

  const f32x4 z4 = {0.f, 0.f, 0.f, 0.f};

  // ---- PE term pre-barrier: s[t] = aqv . sp[16t+c]  (17 independent global loads, 1 RTT;
  // sp rows identical across all 8 waves -> L1 broadcast). Runs while staging completes.
  f32x4 s[17];
#pragma unroll
  for (int t = 0; t < 17; ++t) {
    const bf16x8 bsp = *reinterpret_cast<const bf16x8*>(sp_h + (size_t)(16 * t + c) * HD + g8);
    s[t] = __builtin_amdgcn_mfma_f32_16x16x32_bf16(aqv, bsp, z4, 0, 0, 0);
  }

  // complete staging: ds_writes + barrier
#pragma unroll
  for (int it = 0; it < 3; ++it) {
    const int p = tid + it * 512;
    *reinterpret_cast<i32x4*>(&qu_sh[(p >> 2) * SP + (p & 3) * 8]) = stq[it];
  }
  __syncthreads();

  // realign constants: C/D layout row=(l>>4)*4+reg, col=l&15 (m89-verified);
  // source col = (4g+r-c)&15 (tile-independent), pick tile 16-t vs 15-t by cond.
  int sl[4]; bool cond[4];
#pragma unroll
  for (int r = 0; r < 4; ++r) {
    sl[r] = 16 * g + ((4 * g + r - c) & 15);
    cond[r] = (4 * g + r) >= c;
  }

  // ---- band term post-barrier: step U computes j-space tile T=U, folds into s[16-U].
  f32x4 shp;
#pragma unroll
  for (int U = 0; U <= 16; ++U) {
    const bf16x8 bqu = *reinterpret_cast<const bf16x8*>(&qu_sh[(16 * w + 16 * U + c) * SP + g8]);
    const f32x4 c1 = __builtin_amdgcn_mfma_f32_16x16x32_bf16(ak, bqu, z4, 0, 0, 0);

    f32x4 shc;
#pragma unroll
    for (int r = 0; r < 4; ++r) shc[r] = __shfl(c1[r], sl[r], 64);

    if (U == 0) {
#pragma unroll
      for (int r = 0; r < 4; ++r)
        s[16][r] = (c == 0) ? (s[16][r] + shc[r]) : -1e30f;  // m=256+c valid only c==0
    } else {
#pragma unroll
      for (int r = 0; r < 4; ++r)
        s[16 - U][r] += cond[r] ? shc[r] : shp[r];
    }
    shp = shc;
  }

  // per-row softmax, NO max-subtraction (|scores| ~ 1, exact in f32), exp2 domain.
  float wgt[4];
#pragma unroll
  for (int r = 0; r < 4; ++r) {
    float sum = 0.f;
#pragma unroll
    for (int t = 0; t < 17; ++t) {
      const float p = exp2f(s[t][r]);
      s[t][r] = p;
      sum += p;
    }
#pragma unroll
    for (int off = 1; off < 16; off <<= 1) sum += __shfl_xor(sum, off, 16);
    wgt[r] = v4[3 - r] * __builtin_amdgcn_rcpf(sum);  // v[n]/sum, n = n0+127-(16w+4g+r)
  }

  // out[m] += sum_i p * w : regs -> cross-group -> cross-wave (LDS) -> atomics
  __syncthreads();  // all waves done reading qu_sh; reuse as reduction buffer
#pragma unroll
  for (int t = 0; t < 17; ++t) {
    float y = s[t][0] * wgt[0] + s[t][1] * wgt[1] + s[t][2] * wgt[2] + s[t][3] * wgt[3];
    y += __shfl_xor(y, 16, 64);
    y += __shfl_xor(y, 32, 64);
    if (l < 16) red[w * NWP + 16 * t + c] = y;
  }
  __syncthreads();
  for (int m = tid; m < NW; m += 512) {
    float ssum = 0.f;
#pragma unroll
    for (int ww = 0; ww < 8; ++ww) ssum += red[ww * NWP + m];
    atomicAdd(&out[((size_t)b * NW + m) * NH + h], ssum);
  }
}

extern "C" void kernel_launch(void* const* d_in, const int* in_sizes, int n_in,
                              void* d_out, int out_size, void* d_ws, size_t ws_size,
                              hipStream_t stream) {
  const float* x = (const float*)d_in[0];
  const float* Wq = (const float*)d_in[1];
  const float* bq = (const float*)d_in[2];
  const float* Wk = (const float*)d_in[3];
  const float* bk = (const float*)d_in[4];
  const float* Wv = (const float*)d_in[5];
  const float* dpe = (const float*)d_in[6];
  const float* u_pe = (const float*)d_in[7];
  const float* v_pe = (const float*)d_in[8];
  float* out = (float*)d_out;

  const size_t qk_elems = (size_t)NH * NB * NL * HD;  // 2,097,152
  float* vv = (float*)d_ws;                           // 65,536 f32
  unsigned short* qu = (unsigned short*)(vv + (size_t)NH * NB * NL);
  unsigned short* qv = qu + qk_elems;
  unsigned short* kb = qv + qk_elems;
  unsigned short* spt = kb + qk_elems;                // 8*272*32

  hipLaunchKernelGGL(projmm_kernel, dim3(PM_BLK + VV_BLK + SPE_BLK), dim3(256), 0, stream,
                     x, Wq, bq, Wk, bk, Wv, dpe, u_pe, v_pe, qu, qv, kb, vv, spt, out);
  hipLaunchKernelGGL(band_attn_mfma, dim3(NH * NB * (NL / ROWS)), dim3(512), 0, stream,
                     qu, qv, kb, vv, spt, out);
}